// Round 6
// baseline (10721.610 us; speedup 1.0000x reference)
//
#include <hip/hip_runtime.h>

#define TT   64
#define NB   8
#define NN   512
#define HID  128
#define G4   512
#define EE   8192
#define SBLK 16
#define NTHR 512
#define KC   32
#define HLS  (SBLK*HID)           // 2048 floats per h-layer (pitch 128, no pad)
#define CHUNKF (G4*KC)            // 16384 floats = 64KB per chunk buffer

__device__ __forceinline__ float sigf(float x){ return 1.0f/(1.0f+expf(-x)); }

__device__ __forceinline__ void gload16(const float* g, float* l){
  __builtin_amdgcn_global_load_lds(
      (const __attribute__((address_space(1))) void*)g,
      (__attribute__((address_space(3))) void*)l, 16, 0, 0);
}

// Fused 3-layer LSTM scan. 256 blocks x 512 thr (8 waves/CU), 16 seqs/block.
// Thread (gg,sg,kh): 8 gates (ifgo x units {2gg,2gg+1}) x 4 seqs {4sg..4sg+3}
// x k-half kh of each KC=32 chunk. ksplit=2 reduction through dead Wbuf half.
// R4/R5 lessons baked in:
//  - __launch_bounds__(512,1): (512,2) capped VGPR at 128 -> ~100 spilled regs
//    -> 2.6GB scratch traffic that also evicted weights from L2. est need ~185.
//  - w-read swizzle s=4kh+(kg^(gg&3)): 16 addrs/instr over 8 bank groups = 2-way
//    (free); R5's ^(gg&7) w/ 32 addrs was 4-way on every read (2.56e8 conflicts).
//  - h layout pitch 128, slot p=(c8+4kh)+(kg^sg): conflict-free.
__global__ __launch_bounds__(NTHR,1) void lstm_scan(
    const float* __restrict__ x,    const float* __restrict__ wih0,
    const float* __restrict__ whh0, const float* __restrict__ bih0, const float* __restrict__ bhh0,
    const float* __restrict__ wih1, const float* __restrict__ whh1,
    const float* __restrict__ bih1, const float* __restrict__ bhh1,
    const float* __restrict__ wih2, const float* __restrict__ whh2,
    const float* __restrict__ bih2, const float* __restrict__ bhh2,
    float* __restrict__ feats)
{
  __shared__ __align__(16) float Wbuf[2*CHUNKF];     // 128 KB
  __shared__ __align__(16) float hbuf[3*HLS];        // 24 KB
  __shared__ float bsum12[2*G4];                     // 4 KB (layer1/2 bias sums)
  __shared__ float xbuf[SBLK];

  const int tid  = threadIdx.x;
  const int lane = tid & 63, wv = tid >> 6;
  const int kh   = tid & 1;                 // k-half of chunk
  const int sg   = (tid >> 1) & 3;          // seq group (4 seqs)
  const int gg   = tid >> 3;                // unit-pair 0..63
  const int grp  = gg*4 + sg;               // reduction group 0..255
  const int s0   = blockIdx.x * SBLK;
  const int b    = s0 >> 9, n0 = s0 & (NN-1);

  for (int i = tid; i < 3*HLS; i += NTHR) hbuf[i] = 0.0f;
  for (int i = tid; i < G4; i += NTHR){
    bsum12[i]      = bih1[i] + bhh1[i];
    bsum12[G4+i]   = bih2[i] + bhh2[i];
  }

  // layer0 bias + wih0 column in registers (8+8)
  float bjA[8], w0g[8];
  #pragma unroll
  for (int j=0;j<8;j++){
    int r = 2*gg + (j&1) + 128*(j>>1);
    bjA[j] = bih0[r] + bhh0[r];
    w0g[j] = wih0[r];
  }

  // DMA source offsets: call i -> band b=wv*8+i (rows 8b..8b+7).
  // lane: row-local = lane>>3, slot s = lane&7; stored slot s of row r holds
  // logical k4 = (s&4) + ((s&3) ^ (((r&127)>>1)&3)).
  int gofs[8];
  #pragma unroll
  for (int i=0;i<8;i++){
    int bb = wv*8 + i;
    int r  = 8*bb + (lane>>3);
    int s  = lane & 7;
    int k4 = (s&4) + ((s&3) ^ (((r&127)>>1)&3));
    gofs[i] = r*HID + 4*k4;
  }

  float acc[8][4];
  float cst0[2][4], cst1[2][4], cst2[2][4];
  #pragma unroll
  for (int un=0;un<2;un++)
    #pragma unroll
    for (int i=0;i<4;i++){ cst0[un][i]=0.f; cst1[un][i]=0.f; cst2[un][i]=0.f; }

  const int wband = wv*8*256;               // LDS float base of this wave's bands

  // prologue: DMA chunk 0 (whh0, k0=0) -> buf 0
  #pragma unroll
  for (int i=0;i<8;i++) gload16(whh0 + gofs[i], &Wbuf[wband + i*256]);

  #pragma unroll 1
  for (int t=0;t<TT;t++){
    if (tid < SBLK) xbuf[tid] = x[(b*TT + t)*NN + n0 + tid];
    // chunks: 0-3 whh0 | 4-7 wih1 | 8-11 whh1 | 12-15 wih2 | 16-19 whh2
    #pragma unroll 1
    for (int c=0;c<20;c++){
      __syncthreads();                      // drains DMA(c); buf c&1 ready
      int nx = c + 1; if (nx == 20) nx = 0;
      {
        const float* m;
        switch (nx>>2){ case 0: m=whh0; break; case 1: m=wih1; break;
                        case 2: m=whh1; break; case 3: m=wih2; break;
                        default: m=whh2; }
        const float* msrc = m + (nx&3)*KC;
        float* dst = &Wbuf[(nx&1)*CHUNKF + wband];
        #pragma unroll
        for (int i=0;i<8;i++) gload16(msrc + gofs[i], dst + i*256);
      }
      if (c==0 || c==4 || c==12){
        #pragma unroll
        for (int j=0;j<8;j++)
          #pragma unroll
          for (int i=0;i<4;i++) acc[j][i] = 0.f;
      }

      const int hl = (c<8)?0:((c<16)?1:2);
      const int c8 = (c&3)*8;               // f4 base along h row
      const float* wb = &Wbuf[(c&1)*CHUNKF];
      const float* hb = &hbuf[hl*HLS + (4*sg)*HID];

      #pragma unroll
      for (int kg=0;kg<4;kg++){
        const int ws = 4*kh + (kg ^ (gg&3));       // weight stored slot
        const int hp = c8 + 4*kh + (kg ^ sg);      // h stored slot
        float4 w4[8], hv[4];
        #pragma unroll
        for (int j=0;j<8;j++){
          int r = 2*gg + (j&1) + 128*(j>>1);
          w4[j] = *(const float4*)(wb + r*KC + 4*ws);
        }
        #pragma unroll
        for (int i=0;i<4;i++) hv[i] = *(const float4*)(hb + i*HID + 4*hp);
        #pragma unroll
        for (int j=0;j<8;j++)
          #pragma unroll
          for (int i=0;i<4;i++)
            acc[j][i] += w4[j].x*hv[i].x + w4[j].y*hv[i].y
                       + w4[j].z*hv[i].z + w4[j].w*hv[i].w;
      }

      // ---- layer end (c=3,11,19 all odd -> dead buf is buf1) ----
      if (c==3 || c==11 || c==19){
        float* scr = &Wbuf[CHUNKF];         // dead half (prefetch went to buf0)
        const int sw = grp & 7;
        __syncthreads();                    // all compute reads of buf1 done
        if (kh == 1){                       // stage partials
          float* sp = scr + grp*32;
          #pragma unroll
          for (int j=0;j<8;j++)
            *(float4*)(sp + 4*(j^sw)) = make_float4(acc[j][0], acc[j][1],
                                                    acc[j][2], acc[j][3]);
        }
        __syncthreads();
        if (kh == 0){                       // combine + bias + cell
          const float* sp = scr + grp*32;
          #pragma unroll
          for (int j=0;j<8;j++){
            float4 v = *(const float4*)(sp + 4*(j^sw));
            acc[j][0]+=v.x; acc[j][1]+=v.y; acc[j][2]+=v.z; acc[j][3]+=v.w;
          }
          #define CELL_BLOCK(LYR, CST, BJ, XT, LAST)                            \
            _Pragma("unroll")                                                   \
            for (int i=0;i<4;i++){                                              \
              const int sq = 4*sg + i;                                          \
              float h2[2];                                                      \
              _Pragma("unroll")                                                 \
              for (int un=0;un<2;un++){                                         \
                float iv = acc[0+un][i] + BJ[0+un];                             \
                float fv = acc[2+un][i] + BJ[2+un];                             \
                float gv = acc[4+un][i] + BJ[4+un];                             \
                float ov = acc[6+un][i] + BJ[6+un];                             \
                if (XT){ float xv = xbuf[sq];                                   \
                  iv += xv*w0g[0+un]; fv += xv*w0g[2+un];                       \
                  gv += xv*w0g[4+un]; ov += xv*w0g[6+un]; }                     \
                float cn = sigf(fv)*CST[un][i] + sigf(iv)*tanhf(gv);            \
                CST[un][i] = cn;                                                \
                h2[un] = sigf(ov)*tanhf(cn);                                    \
              }                                                                 \
              { int k4 = gg>>1;                                                 \
                int p  = (k4 & ~3) | ((k4&3) ^ sg);                             \
                *(float2*)&hbuf[(LYR)*HLS + sq*HID + 4*p + (2*gg&3)] =          \
                    make_float2(h2[0], h2[1]); }                                \
              if (LAST && t==TT-1)                                              \
                *(float2*)&feats[(s0+sq)*HID + 2*gg] = make_float2(h2[0], h2[1]); \
            }
          if (c==3){
            CELL_BLOCK(0, cst0, bjA, 1, 0)
          } else if (c==11){
            float bjt[8];
            #pragma unroll
            for (int j=0;j<8;j++) bjt[j] = bsum12[2*gg + (j&1) + 128*(j>>1)];
            CELL_BLOCK(1, cst1, bjt, 0, 0)
          } else {
            float bjt[8];
            #pragma unroll
            for (int j=0;j<8;j++) bjt[j] = bsum12[G4 + 2*gg + (j&1) + 128*(j>>1)];
            CELL_BLOCK(2, cst2, bjt, 0, 1)
          }
          #undef CELL_BLOCK
        }
        // next phase-top __syncthreads publishes hbuf
      }
    }
  }
}

// xl = in @ W^T ; optional input transform relu(in + pre_bias)
template<int KOUT>
__global__ void gcn_gemm(const float* __restrict__ in, const float* __restrict__ W,
                         const float* __restrict__ pre_bias, float* __restrict__ out)
{
  int id  = blockIdx.x*256 + threadIdx.x;
  int row = id / KOUT;
  int o   = id & (KOUT-1);
  const float4* a4 = (const float4*)(in + row*HID);
  const float4* w4 = (const float4*)(W + o*HID);
  float acc = 0.f;
  if (pre_bias){
    const float4* b4 = (const float4*)pre_bias;
    #pragma unroll 8
    for (int k=0;k<HID/4;k++){
      float4 av=a4[k], wv=w4[k], bv=b4[k];
      acc += fmaxf(av.x+bv.x,0.f)*wv.x + fmaxf(av.y+bv.y,0.f)*wv.y
           + fmaxf(av.z+bv.z,0.f)*wv.z + fmaxf(av.w+bv.w,0.f)*wv.w;
    }
  } else {
    #pragma unroll 8
    for (int k=0;k<HID/4;k++){
      float4 av=a4[k], wv=w4[k];
      acc += av.x*wv.x + av.y*wv.y + av.z*wv.z + av.w*wv.w;
    }
  }
  out[id] = acc;
}

__global__ void deg_init(float* deg){
  int i = blockIdx.x*256 + threadIdx.x;
  if (i < NN) deg[i] = 1.0f;             // self-loop
}
__global__ void deg_edges(const int* __restrict__ ei, float* deg){
  int e = blockIdx.x*256 + threadIdx.x;
  if (e < EE) atomicAdd(&deg[ei[EE+e]], 1.0f);
}
// dense normalized adjacency: A[dst][src] += dis[src]*dis[dst]; diag += 1/deg
__global__ void build_A(const int* __restrict__ ei, const float* __restrict__ deg,
                        float* __restrict__ A){
  int e = blockIdx.x*256 + threadIdx.x;
  if (e < EE){
    int s = ei[e], d = ei[EE+e];
    atomicAdd(&A[d*NN+s], rsqrtf(deg[s])*rsqrtf(deg[d]));
  } else if (e < EE+NN){
    int n = e - EE;
    atomicAdd(&A[n*NN+n], 1.0f/deg[n]);
  }
}

// Y[b,n,:] = sum_m A[n,m] * X[b,m,:]  (dense aggregation, 16 rows/block)
template<int KOUT>
__global__ __launch_bounds__(512) void gcn_agg(const float* __restrict__ A,
    const float* __restrict__ X, float* __restrict__ Y)
{
  const int F4 = KOUT/4;
  const int TN = 16;
  __shared__ __align__(16) float As[TN*NN];
  const int b = blockIdx.x, n0 = blockIdx.y*TN;
  const int tid = threadIdx.x;
  const int f4 = tid & (F4-1), nr = tid / F4;
  for (int i = tid; i < TN*NN; i += TN*F4) As[i] = A[n0*NN + i];
  __syncthreads();
  const float* Xb = X + b*NN*KOUT + f4*4;
  const float* Ar = As + nr*NN;
  float4 s = {0,0,0,0};
  #pragma unroll 4
  for (int m=0;m<NN;m++){
    float a = Ar[m];
    float4 xv = *(const float4*)(Xb + m*KOUT);
    s.x += a*xv.x; s.y += a*xv.y; s.z += a*xv.z; s.w += a*xv.w;
  }
  *(float4*)(Y + (b*NN + n0 + nr)*KOUT + f4*4) = s;
}

// out[b] = mean_n relu(agg2+b2) . cls_w + cls_b
__global__ void finalize(const float* __restrict__ agg2, const float* __restrict__ b2,
                         const float* __restrict__ clw, const float* __restrict__ clb,
                         float* __restrict__ out)
{
  __shared__ float red[256];
  int bb = blockIdx.x, tid = threadIdx.x;
  float acc = 0.f;
  for (int i = tid; i < NN*64; i += 256){
    int j = i & 63;
    float v = agg2[bb*NN*64 + i] + b2[j];
    acc += fmaxf(v, 0.f) * clw[j];
  }
  red[tid] = acc; __syncthreads();
  for (int sfd=128; sfd>0; sfd>>=1){
    if (tid < sfd) red[tid] += red[tid+sfd];
    __syncthreads();
  }
  if (tid==0) out[bb] = red[0]*(1.0f/NN) + clb[0];
}

extern "C" void kernel_launch(void* const* d_in, const int* in_sizes, int n_in,
                              void* d_out, int out_size, void* d_ws, size_t ws_size,
                              hipStream_t stream)
{
  const float* x    = (const float*)d_in[0];
  const int*   ei   = (const int*)  d_in[1];
  const float* wih0 = (const float*)d_in[2];
  const float* whh0 = (const float*)d_in[3];
  const float* bih0 = (const float*)d_in[4];
  const float* bhh0 = (const float*)d_in[5];
  const float* wih1 = (const float*)d_in[6];
  const float* whh1 = (const float*)d_in[7];
  const float* bih1 = (const float*)d_in[8];
  const float* bhh1 = (const float*)d_in[9];
  const float* wih2 = (const float*)d_in[10];
  const float* whh2 = (const float*)d_in[11];
  const float* bih2 = (const float*)d_in[12];
  const float* bhh2 = (const float*)d_in[13];
  const float* g1w  = (const float*)d_in[14];
  const float* g1b  = (const float*)d_in[15];
  const float* g2w  = (const float*)d_in[16];
  const float* g2b  = (const float*)d_in[17];
  const float* clw  = (const float*)d_in[18];
  const float* clb  = (const float*)d_in[19];
  float* out = (float*)d_out;

  char* ws = (char*)d_ws;
  float* feats = (float*)(ws);                 // [4096,128]  2 MB
  float* xl1   = (float*)(ws + 2097152);       // [8,512,128] 2 MB
  float* agg1  = (float*)(ws + 4194304);       // [8,512,128] 2 MB
  float* xl2   = (float*)(ws + 6291456);       // [8,512,64]  1 MB
  float* agg2  = (float*)(ws + 7340032);       // [8,512,64]  1 MB
  float* A     = (float*)(ws + 8388608);       // [512,512]   1 MB
  float* deg   = (float*)(ws + 9437184);       // [512]

  hipMemsetAsync(A, 0, NN*NN*sizeof(float), stream);
  deg_init <<<2, 256, 0, stream>>>(deg);
  deg_edges<<<EE/256, 256, 0, stream>>>(ei, deg);
  build_A  <<<(EE+NN+255)/256, 256, 0, stream>>>(ei, deg, A);

  lstm_scan<<<256, NTHR, 0, stream>>>(x, wih0, whh0, bih0, bhh0,
      wih1, whh1, bih1, bhh1, wih2, whh2, bih2, bhh2, feats);

  gcn_gemm<128><<<(4096*128)/256, 256, 0, stream>>>(feats, g1w, nullptr, xl1);
  gcn_agg<128><<<dim3(NB, NN/16), 512, 0, stream>>>(A, xl1, agg1);
  gcn_gemm<64><<<(4096*64)/256, 256, 0, stream>>>(agg1, g2w, g1b, xl2);
  gcn_agg<64><<<dim3(NB, NN/16), 256, 0, stream>>>(A, xl2, agg2);
  finalize<<<NB, 256, 0, stream>>>(agg2, g2b, clw, clb, out);
}

// Round 7
// 6599.982 us; speedup vs baseline: 1.6245x; 1.6245x over previous
//
#include <hip/hip_runtime.h>

#define TT   64
#define NB   8
#define NN   512
#define HID  128
#define G4   512
#define EE   8192
#define SBLK 8                    // sequences per block
#define NTHR 256                  // threads per block (4 waves)
#define KC   16                   // k-chunk (floats)
#define HP   132                  // hbuf row pitch (floats)
#define PLANE 516                 // f4-slots per k-plane in LDS (512 data + 4 pad)
#define CHUNK_FL (4*PLANE*4)      // 8256 floats = 33024 B per chunk buffer

__device__ __forceinline__ float sigf(float x){ return 1.0f/(1.0f+expf(-x)); }

__device__ __forceinline__ void gload16(const float* g, float* l){
  __builtin_amdgcn_global_load_lds(
      (const __attribute__((address_space(1))) void*)g,
      (__attribute__((address_space(3))) void*)l, 16, 0, 0);
}

// Fused 3-layer LSTM scan. 512 blocks x 256 thr, 2 blocks/CU (8 waves/CU),
// 8 seqs/block. Thread (gg,kq): 8 gate rows (ifgo x units {2gg,2gg+1}) x all
// 8 seqs x k-quarter kq (4 ks) of each KC=16 chunk. ksplit4 reduction through
// the dead LDS chunk buffer at each layer end; cell update on kq==0.
// Hard-won constraints baked in (R2-R6):
//  - 256-thr blocks: compiler grants 256 VGPRs (512-thr blocks get capped at
//    ~128 -> giant spill traffic that also evicts weights from L2).
//  - 2 blocks/CU: LDS <= 78.8KB/block; restores 8 waves/CU latency hiding.
//  - All register arrays constant-indexed (no alloca/scratch).
//  - W LDS layout: plane stride 516 f4, rows de-interleaved (even 0..255,
//    odd 256..511) -> w-reads hit exactly 8 addrs/bank-quad = b128 BW floor;
//    h-reads are 4-addr x 16-lane broadcasts (free).
__global__ __launch_bounds__(NTHR,2) void lstm_scan(
    const float* __restrict__ x,    const float* __restrict__ wih0,
    const float* __restrict__ whh0, const float* __restrict__ bih0, const float* __restrict__ bhh0,
    const float* __restrict__ wih1, const float* __restrict__ whh1,
    const float* __restrict__ bih1, const float* __restrict__ bhh1,
    const float* __restrict__ wih2, const float* __restrict__ whh2,
    const float* __restrict__ bih2, const float* __restrict__ bhh2,
    float* __restrict__ feats)
{
  __shared__ __align__(16) float Wbuf[2*CHUNK_FL];   // 66048 B
  __shared__ __align__(16) float hbuf[3*SBLK*HP];    // 12672 B
  __shared__ float xbuf[SBLK];

  const int tid  = threadIdx.x;
  const int lane = tid & 63, wv = tid >> 6;          // wv = DMA k-plane
  const int kq   = tid & 3;                          // compute k-quarter
  const int gg   = tid >> 2;                         // unit-pair 0..63
  const int s0   = blockIdx.x * SBLK;
  const int b    = s0 >> 9, n0 = s0 & (NN-1);

  for (int i = tid; i < 3*SBLK*HP; i += NTHR) hbuf[i] = 0.0f;

  // thread's 8 gate rows: r(j) = 2gg + (j&1) + 128*(j>>1); j = 2*type+un
  float bjA[8], bjB[8], bjC[8], w0g[8];
  #pragma unroll
  for (int j=0;j<8;j++){
    int r = 2*gg + (j&1) + 128*(j>>1);
    bjA[j] = bih0[r] + bhh0[r];
    bjB[j] = bih1[r] + bhh1[r];
    bjC[j] = bih2[r] + bhh2[r];
    w0g[j] = wih0[r];
  }

  // DMA source offsets: wave wv fills k-plane wv. Instr i covers LDS f4-slots
  // 516*wv + 64*i + lane; de-interleaved row = 2*(pos&255) + (pos>>8).
  int gofs[9];
  #pragma unroll
  for (int i=0;i<9;i++){
    int pos = 64*i + lane;
    int r   = (pos < 512) ? (2*(pos & 255) + (pos >> 8)) : 0;
    gofs[i] = r*HID + 4*wv;
  }

  // compute-side W offsets (float): 4*(516*kq + pos_j), pos_j = gg+64ty+256un
  int wq[8];
  #pragma unroll
  for (int j=0;j<8;j++)
    wq[j] = 4*(PLANE*kq + gg + 64*(j>>1) + 256*(j&1));

  float acc[8][8];
  float cst0[2][8], cst1[2][8], cst2[2][8];
  #pragma unroll
  for (int un=0;un<2;un++)
    #pragma unroll
    for (int i=0;i<8;i++){ cst0[un][i]=0.f; cst1[un][i]=0.f; cst2[un][i]=0.f; }

  // prologue: DMA chunk 0 (whh0, k0=0) -> buf 0
  #pragma unroll
  for (int i=0;i<9;i++)
    if (64*i + lane < 4*PLANE/4)   // pos < 516
      gload16(whh0 + gofs[i], &Wbuf[wv*(PLANE*4) + i*256]);

  #pragma unroll 1
  for (int t=0;t<TT;t++){
    if (tid < SBLK) xbuf[tid] = x[(b*TT + t)*NN + n0 + tid];
    // chunks: c>>3 selects {whh0,wih1,whh1,wih2,whh2}; k0 = (c&7)*KC
    #pragma unroll 1
    for (int c=0;c<40;c++){
      __syncthreads();                      // drains DMA(c); buf c&1 ready
      int nx = c + 1; if (nx == 40) nx = 0;
      {
        const float* m;
        switch (nx>>3){ case 0: m=whh0; break; case 1: m=wih1; break;
                        case 2: m=whh1; break; case 3: m=wih2; break;
                        default: m=whh2; }
        const float* msrc = m + (nx&7)*KC;
        float* dst = &Wbuf[(nx&1)*CHUNK_FL + wv*(PLANE*4)];
        #pragma unroll
        for (int i=0;i<9;i++)
          if (64*i + lane < PLANE)
            gload16(msrc + gofs[i], dst + i*256);
      }
      if (c==0 || c==8 || c==24){
        #pragma unroll
        for (int j=0;j<8;j++)
          #pragma unroll
          for (int i=0;i<8;i++) acc[j][i] = 0.f;
      }

      const int hl = (c<16)?0:((c<32)?1:2);
      const float* wp = &Wbuf[(c&1)*CHUNK_FL];
      const float* hp = &hbuf[hl*SBLK*HP + 16*(c&7) + 4*kq];

      float4 w4[8], hv[8];
      #pragma unroll
      for (int j=0;j<8;j++) w4[j] = *(const float4*)(wp + wq[j]);
      #pragma unroll
      for (int i=0;i<8;i++) hv[i] = *(const float4*)(hp + i*HP);
      #pragma unroll
      for (int j=0;j<8;j++)
        #pragma unroll
        for (int i=0;i<8;i++)
          acc[j][i] += w4[j].x*hv[i].x + w4[j].y*hv[i].y
                     + w4[j].z*hv[i].z + w4[j].w*hv[i].w;

      // ---- layer end (c=7,23,39: odd -> dead buffer is buf1) ----
      if (c==7 || c==23 || c==39){
        float* scr = &Wbuf[CHUNK_FL];       // buf1; prefetch went to buf0
        const int swz = gg & 15;
        __syncthreads();                    // compute reads of buf1 done
        if (kq >= 2){                       // stage A write: idx (kq-2)*64+gg
          float* sp = scr + ((kq-2)*64 + gg)*64;
          #pragma unroll
          for (int j=0;j<8;j++)
            #pragma unroll
            for (int i4=0;i4<2;i4++)
              *(float4*)(sp + 4*((2*j+i4)^swz)) =
                  make_float4(acc[j][4*i4],acc[j][4*i4+1],acc[j][4*i4+2],acc[j][4*i4+3]);
        }
        __syncthreads();
        if (kq < 2){                        // stage A add from partner kq+2
          const float* sp = scr + (kq*64 + gg)*64;
          #pragma unroll
          for (int j=0;j<8;j++)
            #pragma unroll
            for (int i4=0;i4<2;i4++){
              float4 v = *(const float4*)(sp + 4*((2*j+i4)^swz));
              acc[j][4*i4]+=v.x; acc[j][4*i4+1]+=v.y;
              acc[j][4*i4+2]+=v.z; acc[j][4*i4+3]+=v.w;
            }
        }
        __syncthreads();
        if (kq == 1){                       // stage B write: idx gg
          float* sp = scr + gg*64;
          #pragma unroll
          for (int j=0;j<8;j++)
            #pragma unroll
            for (int i4=0;i4<2;i4++)
              *(float4*)(sp + 4*((2*j+i4)^swz)) =
                  make_float4(acc[j][4*i4],acc[j][4*i4+1],acc[j][4*i4+2],acc[j][4*i4+3]);
        }
        __syncthreads();
        if (kq == 0){                       // stage B add + bias + cell
          const float* sp = scr + gg*64;
          #pragma unroll
          for (int j=0;j<8;j++)
            #pragma unroll
            for (int i4=0;i4<2;i4++){
              float4 v = *(const float4*)(sp + 4*((2*j+i4)^swz));
              acc[j][4*i4]+=v.x; acc[j][4*i4+1]+=v.y;
              acc[j][4*i4+2]+=v.z; acc[j][4*i4+3]+=v.w;
            }
          #define CELL_BLOCK(LYR, CST, BJ, XT, LAST)                            \
            _Pragma("unroll")                                                   \
            for (int i=0;i<8;i++){                                              \
              float h2[2];                                                      \
              _Pragma("unroll")                                                 \
              for (int un=0;un<2;un++){                                         \
                float iv = acc[0+un][i] + BJ[0+un];                             \
                float fv = acc[2+un][i] + BJ[2+un];                             \
                float gv = acc[4+un][i] + BJ[4+un];                             \
                float ov = acc[6+un][i] + BJ[6+un];                             \
                if (XT){ float xv = xbuf[i];                                    \
                  iv += xv*w0g[0+un]; fv += xv*w0g[2+un];                       \
                  gv += xv*w0g[4+un]; ov += xv*w0g[6+un]; }                     \
                float cn = sigf(fv)*CST[un][i] + sigf(iv)*tanhf(gv);            \
                CST[un][i] = cn;                                                \
                h2[un] = sigf(ov)*tanhf(cn);                                    \
              }                                                                 \
              *(float2*)&hbuf[(LYR)*SBLK*HP + i*HP + 2*gg] = make_float2(h2[0], h2[1]); \
              if (LAST && t==TT-1)                                              \
                *(float2*)&feats[(s0+i)*HID + 2*gg] = make_float2(h2[0], h2[1]); \
            }
          if      (c==7 ){ CELL_BLOCK(0, cst0, bjA, 1, 0) }
          else if (c==23){ CELL_BLOCK(1, cst1, bjB, 0, 0) }
          else           { CELL_BLOCK(2, cst2, bjC, 0, 1) }
          #undef CELL_BLOCK
        }
        // next phase-top __syncthreads publishes hbuf
      }
    }
  }
}

// xl = in @ W^T ; optional input transform relu(in + pre_bias)
template<int KOUT>
__global__ void gcn_gemm(const float* __restrict__ in, const float* __restrict__ W,
                         const float* __restrict__ pre_bias, float* __restrict__ out)
{
  int id  = blockIdx.x*256 + threadIdx.x;
  int row = id / KOUT;
  int o   = id & (KOUT-1);
  const float4* a4 = (const float4*)(in + row*HID);
  const float4* w4 = (const float4*)(W + o*HID);
  float acc = 0.f;
  if (pre_bias){
    const float4* b4 = (const float4*)pre_bias;
    #pragma unroll 8
    for (int k=0;k<HID/4;k++){
      float4 av=a4[k], wv=w4[k], bv=b4[k];
      acc += fmaxf(av.x+bv.x,0.f)*wv.x + fmaxf(av.y+bv.y,0.f)*wv.y
           + fmaxf(av.z+bv.z,0.f)*wv.z + fmaxf(av.w+bv.w,0.f)*wv.w;
    }
  } else {
    #pragma unroll 8
    for (int k=0;k<HID/4;k++){
      float4 av=a4[k], wv=w4[k];
      acc += av.x*wv.x + av.y*wv.y + av.z*wv.z + av.w*wv.w;
    }
  }
  out[id] = acc;
}

__global__ void deg_init(float* deg){
  int i = blockIdx.x*256 + threadIdx.x;
  if (i < NN) deg[i] = 1.0f;             // self-loop
}
__global__ void deg_edges(const int* __restrict__ ei, float* deg){
  int e = blockIdx.x*256 + threadIdx.x;
  if (e < EE) atomicAdd(&deg[ei[EE+e]], 1.0f);
}
// dense normalized adjacency: A[dst][src] += dis[src]*dis[dst]; diag += 1/deg
__global__ void build_A(const int* __restrict__ ei, const float* __restrict__ deg,
                        float* __restrict__ A){
  int e = blockIdx.x*256 + threadIdx.x;
  if (e < EE){
    int s = ei[e], d = ei[EE+e];
    atomicAdd(&A[d*NN+s], rsqrtf(deg[s])*rsqrtf(deg[d]));
  } else if (e < EE+NN){
    int n = e - EE;
    atomicAdd(&A[n*NN+n], 1.0f/deg[n]);
  }
}

// Y[b,n,:] = sum_m A[n,m] * X[b,m,:]  (dense aggregation, 16 rows/block)
template<int KOUT>
__global__ __launch_bounds__(512) void gcn_agg(const float* __restrict__ A,
    const float* __restrict__ X, float* __restrict__ Y)
{
  const int F4 = KOUT/4;
  const int TN = 16;
  __shared__ __align__(16) float As[TN*NN];
  const int b = blockIdx.x, n0 = blockIdx.y*TN;
  const int tid = threadIdx.x;
  const int f4 = tid & (F4-1), nr = tid / F4;
  for (int i = tid; i < TN*NN; i += TN*F4) As[i] = A[n0*NN + i];
  __syncthreads();
  const float* Xb = X + b*NN*KOUT + f4*4;
  const float* Ar = As + nr*NN;
  float4 s = {0,0,0,0};
  #pragma unroll 4
  for (int m=0;m<NN;m++){
    float a = Ar[m];
    float4 xv = *(const float4*)(Xb + m*KOUT);
    s.x += a*xv.x; s.y += a*xv.y; s.z += a*xv.z; s.w += a*xv.w;
  }
  *(float4*)(Y + (b*NN + n0 + nr)*KOUT + f4*4) = s;
}

// out[b] = mean_n relu(agg2+b2) . cls_w + cls_b
__global__ void finalize(const float* __restrict__ agg2, const float* __restrict__ b2,
                         const float* __restrict__ clw, const float* __restrict__ clb,
                         float* __restrict__ out)
{
  __shared__ float red[256];
  int bb = blockIdx.x, tid = threadIdx.x;
  float acc = 0.f;
  for (int i = tid; i < NN*64; i += 256){
    int j = i & 63;
    float v = agg2[bb*NN*64 + i] + b2[j];
    acc += fmaxf(v, 0.f) * clw[j];
  }
  red[tid] = acc; __syncthreads();
  for (int sfd=128; sfd>0; sfd>>=1){
    if (tid < sfd) red[tid] += red[tid+sfd];
    __syncthreads();
  }
  if (tid==0) out[bb] = red[0]*(1.0f/NN) + clb[0];
}

extern "C" void kernel_launch(void* const* d_in, const int* in_sizes, int n_in,
                              void* d_out, int out_size, void* d_ws, size_t ws_size,
                              hipStream_t stream)
{
  const float* x    = (const float*)d_in[0];
  const int*   ei   = (const int*)  d_in[1];
  const float* wih0 = (const float*)d_in[2];
  const float* whh0 = (const float*)d_in[3];
  const float* bih0 = (const float*)d_in[4];
  const float* bhh0 = (const float*)d_in[5];
  const float* wih1 = (const float*)d_in[6];
  const float* whh1 = (const float*)d_in[7];
  const float* bih1 = (const float*)d_in[8];
  const float* bhh1 = (const float*)d_in[9];
  const float* wih2 = (const float*)d_in[10];
  const float* whh2 = (const float*)d_in[11];
  const float* bih2 = (const float*)d_in[12];
  const float* bhh2 = (const float*)d_in[13];
  const float* g1w  = (const float*)d_in[14];
  const float* g1b  = (const float*)d_in[15];
  const float* g2w  = (const float*)d_in[16];
  const float* g2b  = (const float*)d_in[17];
  const float* clw  = (const float*)d_in[18];
  const float* clb  = (const float*)d_in[19];
  float* out = (float*)d_out;

  char* ws = (char*)d_ws;
  float* feats = (float*)(ws);                 // [4096,128]  2 MB
  float* xl1   = (float*)(ws + 2097152);       // [8,512,128] 2 MB
  float* agg1  = (float*)(ws + 4194304);       // [8,512,128] 2 MB
  float* xl2   = (float*)(ws + 6291456);       // [8,512,64]  1 MB
  float* agg2  = (float*)(ws + 7340032);       // [8,512,64]  1 MB
  float* A     = (float*)(ws + 8388608);       // [512,512]   1 MB
  float* deg   = (float*)(ws + 9437184);       // [512]

  hipMemsetAsync(A, 0, NN*NN*sizeof(float), stream);
  deg_init <<<2, 256, 0, stream>>>(deg);
  deg_edges<<<EE/256, 256, 0, stream>>>(ei, deg);
  build_A  <<<(EE+NN+255)/256, 256, 0, stream>>>(ei, deg, A);

  lstm_scan<<<512, NTHR, 0, stream>>>(x, wih0, whh0, bih0, bhh0,
      wih1, whh1, bih1, bhh1, wih2, whh2, bih2, bhh2, feats);

  gcn_gemm<128><<<(4096*128)/256, 256, 0, stream>>>(feats, g1w, nullptr, xl1);
  gcn_agg<128><<<dim3(NB, NN/16), 512, 0, stream>>>(A, xl1, agg1);
  gcn_gemm<64><<<(4096*64)/256, 256, 0, stream>>>(agg1, g2w, g1b, xl2);
  gcn_agg<64><<<dim3(NB, NN/16), 256, 0, stream>>>(A, xl2, agg2);
  finalize<<<NB, 256, 0, stream>>>(agg2, g2b, clw, clb, out);
}